// Round 3
// baseline (1851.201 us; speedup 1.0000x reference)
//
#include <hip/hip_runtime.h>
#include <math.h>

#define F 32
#define K 16
#define EPSN 1e-8f

// ---------------------------------------------------------------------------
// Pre-pass: normalize all W rows into d_ws.
// Workspace layout: per degree d (1..4), K focal rows then K*d neighbor rows
// (flat k*d+j), each row F floats. Row offsets: deg1=0, deg2=32, deg3=80,
// deg4=144; total 224 rows (28 KB).
// ---------------------------------------------------------------------------
struct NormArgs {
    const float* Wf[4];
    const float* Wn[4];
    float*       dst[4];
};

__global__ __launch_bounds__(128)
void norm_w_kernel(NormArgs n)
{
    const int d   = blockIdx.x;            // 0..3  (DEG = d+1)
    const int DEG = d + 1;
    const int nrows = K * (1 + DEG);
    const int r = threadIdx.x;
    if (r >= nrows) return;
    const float* src = (r < K) ? (n.Wf[d] + r * F) : (n.Wn[d] + (r - K) * F);
    float ss = 0.f;
    #pragma unroll
    for (int f = 0; f < F; ++f) { float v = src[f]; ss += v * v; }
    const float sc = 1.f / (sqrtf(ss) + EPSN);
    float* dst = n.dst[d] + r * F;
    #pragma unroll
    for (int f = 0; f < F; ++f) dst[f] = src[f] * sc;
}

// ---------------------------------------------------------------------------
// Main kernel (scalar-W path): W reads are wave-uniform with compile-time
// offsets -> s_load into SGPRs (scalar pipe, otherwise idle). No LDS at all.
// Control flow kept uniform (index clamp + predicated stores).
// ---------------------------------------------------------------------------
template<int DEG>
__device__ __forceinline__ void process_deg(const float* __restrict__ x,
                                            const int*   __restrict__ sel,
                                            const int*   __restrict__ nei,
                                            const float* __restrict__ wn,
                                            float* __restrict__ out,
                                            int nd, int i0)
{
    const int tid = threadIdx.x;
    int i = i0 + tid;
    const bool valid = (i < nd);
    if (!valid) i = nd - 1;                 // clamp: keep control flow uniform

    const int node = sel[i];
    int nn[DEG];
    #pragma unroll
    for (int j = 0; j < DEG; ++j) nn[j] = nei[i * DEG + j];

    // zero quadrants first: stores drain under the gather latency
    float4* o = (float4*)(out + (size_t)node * (4 * K));
    const float4 z = make_float4(0.f, 0.f, 0.f, 0.f);
    if (valid) {
        #pragma unroll
        for (int b = 0; b < 4; ++b) {
            if (b != DEG - 1) {
                o[b * 4 + 0] = z; o[b * 4 + 1] = z;
                o[b * 4 + 2] = z; o[b * 4 + 3] = z;
            }
        }
    }

    float acc[K];

    #pragma unroll
    for (int r = 0; r <= DEG; ++r) {
        const float* xr = x + (size_t)((r == 0) ? node : nn[r - 1]) * F;
        float4 rv[F / 4];
        #pragma unroll
        for (int q = 0; q < F / 4; ++q) rv[q] = ((const float4*)xr)[q];

        float ss = 0.f;
        #pragma unroll
        for (int q = 0; q < F / 4; ++q)
            ss += rv[q].x * rv[q].x + rv[q].y * rv[q].y
                + rv[q].z * rv[q].z + rv[q].w * rv[q].w;
        float sc = 1.f / (sqrtf(ss) + EPSN);
        if (r > 0) sc *= (1.f / (float)DEG);

        // pre-scale the row once; dots then accumulate straight into acc[k]
        #pragma unroll
        for (int q = 0; q < F / 4; ++q) {
            rv[q].x *= sc; rv[q].y *= sc; rv[q].z *= sc; rv[q].w *= sc;
        }

        #pragma unroll
        for (int k = 0; k < K; ++k) {
            // compile-time row offset -> uniform address -> s_load
            const float* w = wn + (size_t)((r == 0) ? k
                                                    : (K + k * DEG + (r - 1))) * F;
            float s = 0.f;
            #pragma unroll
            for (int q = 0; q < F / 4; ++q) {
                const float4 w4 = *(const float4*)(w + q * 4);
                s += w4.x * rv[q].x + w4.y * rv[q].y
                   + w4.z * rv[q].z + w4.w * rv[q].w;
            }
            if (r == 0) acc[k] = s; else acc[k] += s;
        }
    }

    if (valid) {
        const int b = DEG - 1;
        o[b * 4 + 0] = make_float4(acc[0],  acc[1],  acc[2],  acc[3]);
        o[b * 4 + 1] = make_float4(acc[4],  acc[5],  acc[6],  acc[7]);
        o[b * 4 + 2] = make_float4(acc[8],  acc[9],  acc[10], acc[11]);
        o[b * 4 + 3] = make_float4(acc[12], acc[13], acc[14], acc[15]);
    }
}

struct Args {
    const float* x;
    const int*   sel[4];
    const int*   nei[4];
    const float* wn[4];    // normalized W (in d_ws), per degree
    int nd[4];
    int bcum[4];
};

// (256, 4): cap VGPR at 128 (natural need ~85) -> 4 waves/SIMD, no spill
// risk. NO local array may be runtime-indexed / address-taken (rule #20 —
// round 1's buf[2] pointer went to scratch and cost 2 GB of spill traffic).
__global__ __launch_bounds__(256, 4)
void fused_kernel(Args a, float* __restrict__ out)
{
    const int bid = blockIdx.x;
    if (bid < a.bcum[0]) {
        process_deg<1>(a.x, a.sel[0], a.nei[0], a.wn[0], out,
                       a.nd[0], bid * 256);
    } else if (bid < a.bcum[1]) {
        process_deg<2>(a.x, a.sel[1], a.nei[1], a.wn[1], out,
                       a.nd[1], (bid - a.bcum[0]) * 256);
    } else if (bid < a.bcum[2]) {
        process_deg<3>(a.x, a.sel[2], a.nei[2], a.wn[2], out,
                       a.nd[2], (bid - a.bcum[1]) * 256);
    } else {
        process_deg<4>(a.x, a.sel[3], a.nei[3], a.wn[3], out,
                       a.nd[3], (bid - a.bcum[2]) * 256);
    }
}

// ---------------------------------------------------------------------------
// Fallback (LDS-based, round-0 structure) in case ws_size is too small.
// ---------------------------------------------------------------------------
template<int DEG>
__device__ __forceinline__ void process_deg_lds(const float* __restrict__ x,
                                                const int*   __restrict__ sel,
                                                const int*   __restrict__ nei,
                                                const float* __restrict__ Wf,
                                                const float* __restrict__ Wn,
                                                float* __restrict__ out,
                                                int nd, int i0, float* sW)
{
    constexpr int NW = K * (1 + DEG);
    const int tid = threadIdx.x;
    if (tid < NW) {
        const float* src = (tid < K) ? (Wf + tid * F) : (Wn + (tid - K) * F);
        float ss = 0.f;
        #pragma unroll
        for (int f = 0; f < F; ++f) { float v = src[f]; ss += v * v; }
        const float sc = 1.f / (sqrtf(ss) + EPSN);
        #pragma unroll
        for (int f = 0; f < F; ++f) sW[tid * F + f] = src[f] * sc;
    }
    __syncthreads();

    const int i = i0 + tid;
    if (i >= nd) return;
    const int node = sel[i];
    int nn[DEG];
    #pragma unroll
    for (int j = 0; j < DEG; ++j) nn[j] = nei[i * DEG + j];

    float acc[K];
    #pragma unroll
    for (int r = 0; r <= DEG; ++r) {
        const float* xr = x + (size_t)((r == 0) ? node : nn[r - 1]) * F;
        float4 rv[F / 4];
        #pragma unroll
        for (int q = 0; q < F / 4; ++q) rv[q] = ((const float4*)xr)[q];
        float ss = 0.f;
        #pragma unroll
        for (int q = 0; q < F / 4; ++q)
            ss += rv[q].x * rv[q].x + rv[q].y * rv[q].y
                + rv[q].z * rv[q].z + rv[q].w * rv[q].w;
        float sc = 1.f / (sqrtf(ss) + EPSN);
        if (r > 0) sc *= (1.f / (float)DEG);
        #pragma unroll
        for (int k = 0; k < K; ++k) {
            const int wrow = (r == 0) ? k : (K + k * DEG + (r - 1));
            float s = 0.f;
            #pragma unroll
            for (int q = 0; q < F / 4; ++q) {
                const float4 w = *(const float4*)&sW[wrow * F + q * 4];
                s += w.x * rv[q].x + w.y * rv[q].y + w.z * rv[q].z + w.w * rv[q].w;
            }
            if (r == 0) acc[k] = s * sc; else acc[k] += s * sc;
        }
    }

    float4* o = (float4*)(out + (size_t)node * (4 * K));
    const float4 z = make_float4(0.f, 0.f, 0.f, 0.f);
    #pragma unroll
    for (int b = 0; b < 4; ++b) {
        if (b == DEG - 1) {
            o[b * 4 + 0] = make_float4(acc[0],  acc[1],  acc[2],  acc[3]);
            o[b * 4 + 1] = make_float4(acc[4],  acc[5],  acc[6],  acc[7]);
            o[b * 4 + 2] = make_float4(acc[8],  acc[9],  acc[10], acc[11]);
            o[b * 4 + 3] = make_float4(acc[12], acc[13], acc[14], acc[15]);
        } else {
            o[b * 4 + 0] = z; o[b * 4 + 1] = z; o[b * 4 + 2] = z; o[b * 4 + 3] = z;
        }
    }
}

struct ArgsLds {
    const float* x;
    const int*   sel[4];
    const int*   nei[4];
    const float* Wf[4];
    const float* Wn[4];
    int nd[4];
    int bcum[4];
};

__global__ __launch_bounds__(256)
void fused_kernel_lds(ArgsLds a, float* __restrict__ out)
{
    __shared__ float sW[K * 5 * F];
    const int bid = blockIdx.x;
    if (bid < a.bcum[0]) {
        process_deg_lds<1>(a.x, a.sel[0], a.nei[0], a.Wf[0], a.Wn[0], out,
                           a.nd[0], bid * 256, sW);
    } else if (bid < a.bcum[1]) {
        process_deg_lds<2>(a.x, a.sel[1], a.nei[1], a.Wf[1], a.Wn[1], out,
                           a.nd[1], (bid - a.bcum[0]) * 256, sW);
    } else if (bid < a.bcum[2]) {
        process_deg_lds<3>(a.x, a.sel[2], a.nei[2], a.Wf[2], a.Wn[2], out,
                           a.nd[2], (bid - a.bcum[1]) * 256, sW);
    } else {
        process_deg_lds<4>(a.x, a.sel[3], a.nei[3], a.Wf[3], a.Wn[3], out,
                           a.nd[3], (bid - a.bcum[2]) * 256, sW);
    }
}

// ---------------------------------------------------------------------------
extern "C" void kernel_launch(void* const* d_in, const int* in_sizes, int n_in,
                              void* d_out, int out_size, void* d_ws, size_t ws_size,
                              hipStream_t stream)
{
    const float* xp = (const float*)d_in[0];
    const int*   selp[4]; const int* neip[4];
    const float* Wfp[4]; const float* Wnp[4];
    int ndv[4];
    for (int d = 0; d < 4; ++d) {
        selp[d] = (const int*)  d_in[1 + 4 * d];
        neip[d] = (const int*)  d_in[2 + 4 * d];
        Wfp[d]  = (const float*)d_in[3 + 4 * d];
        Wnp[d]  = (const float*)d_in[4 + 4 * d];
        ndv[d]  = in_sizes[1 + 4 * d];
    }
    int bcum[4]; int cum = 0;
    for (int d = 0; d < 4; ++d) { cum += (ndv[d] + 255) / 256; bcum[d] = cum; }
    float* out = (float*)d_out;

    const size_t wneed = 224 * F * sizeof(float);   // 28 KB
    if (ws_size >= wneed && d_ws != nullptr) {
        static const int rowoff[4] = {0, 32, 80, 144};  // K*(1+DEG) cumulative
        NormArgs na;
        for (int d = 0; d < 4; ++d) {
            na.Wf[d]  = Wfp[d];
            na.Wn[d]  = Wnp[d];
            na.dst[d] = (float*)d_ws + (size_t)rowoff[d] * F;
        }
        norm_w_kernel<<<4, 128, 0, stream>>>(na);

        Args a;
        a.x = xp;
        for (int d = 0; d < 4; ++d) {
            a.sel[d] = selp[d]; a.nei[d] = neip[d];
            a.wn[d]  = (const float*)d_ws + (size_t)rowoff[d] * F;
            a.nd[d]  = ndv[d];   a.bcum[d] = bcum[d];
        }
        fused_kernel<<<cum, 256, 0, stream>>>(a, out);
    } else {
        ArgsLds a;
        a.x = xp;
        for (int d = 0; d < 4; ++d) {
            a.sel[d] = selp[d]; a.nei[d] = neip[d];
            a.Wf[d]  = Wfp[d];  a.Wn[d]  = Wnp[d];
            a.nd[d]  = ndv[d];  a.bcum[d] = bcum[d];
        }
        fused_kernel_lds<<<cum, 256, 0, stream>>>(a, out);
    }
}

// Round 4
// 903.730 us; speedup vs baseline: 2.0484x; 2.0484x over previous
//
#include <hip/hip_runtime.h>
#include <math.h>

#define F 32
#define K 16
#define EPSN 1e-8f

// Per-degree worker: block handles 256 consecutive focal nodes of one degree.
// sW: per-block LDS holding the normalized W rows for this degree
// (rows 0..15 = W_focal, rows 16.. = W_nei flat (k*DEG+j)).
//
// Design notes (hard-won over rounds 1/3):
//  - W lives in LDS, read as uniform-address ds_read_b128 broadcasts. Both
//    attempts to move W elsewhere (double-buffered regs, scalar-pipe global
//    loads) exploded live ranges -> scratch spills -> 2-4 GB of HBM traffic.
//  - Every local array index is compile-time constant after unrolling
//    (rule #20). No address-taken locals.
//  - VGPR capped at 128 via __launch_bounds__(256,4): natural use was 132,
//    which sat just over the 128-VGPR occupancy cliff (2 blocks/CU). The cap
//    doubles resident waves to 16/CU.
template<int DEG>
__device__ __forceinline__ void process_deg(const float* __restrict__ x,
                                            const int*   __restrict__ sel,
                                            const int*   __restrict__ nei,
                                            const float* __restrict__ Wf,
                                            const float* __restrict__ Wn,
                                            float* __restrict__ out,
                                            int nd, int i0, float* sW)
{
    constexpr int NW = K * (1 + DEG);
    const int tid = threadIdx.x;

    // normalize W rows into LDS (one thread per row; NW <= 80)
    if (tid < NW) {
        const float* src = (tid < K) ? (Wf + tid * F) : (Wn + (tid - K) * F);
        float ss = 0.f;
        #pragma unroll
        for (int f = 0; f < F; ++f) { float v = src[f]; ss += v * v; }
        const float sc = 1.f / (sqrtf(ss) + EPSN);
        #pragma unroll
        for (int f = 0; f < F; ++f) sW[tid * F + f] = src[f] * sc;
    }
    __syncthreads();

    const int i = i0 + tid;
    if (i >= nd) return;

    const int node = sel[i];

    // neighbor index loads issue immediately (coalesced)
    int nn[DEG];
    #pragma unroll
    for (int j = 0; j < DEG; ++j) nn[j] = nei[i * DEG + j];

    // Zero quadrants first: these stores depend only on `node`, so they
    // drain under the row-gather latency instead of after it.
    float4* o = (float4*)(out + (size_t)node * (4 * K));
    const float4 z = make_float4(0.f, 0.f, 0.f, 0.f);
    #pragma unroll
    for (int b = 0; b < 4; ++b) {
        if (b != DEG - 1) {
            o[b * 4 + 0] = z; o[b * 4 + 1] = z;
            o[b * 4 + 2] = z; o[b * 4 + 3] = z;
        }
    }

    float acc[K];

    #pragma unroll
    for (int r = 0; r <= DEG; ++r) {
        const float* xr = x + (size_t)((r == 0) ? node : nn[r - 1]) * F;
        float4 rv[F / 4];
        #pragma unroll
        for (int q = 0; q < F / 4; ++q) rv[q] = ((const float4*)xr)[q];

        float ss = 0.f;
        #pragma unroll
        for (int q = 0; q < F / 4; ++q)
            ss += rv[q].x * rv[q].x + rv[q].y * rv[q].y
                + rv[q].z * rv[q].z + rv[q].w * rv[q].w;
        float sc = 1.f / (sqrtf(ss) + EPSN);
        if (r > 0) sc *= (1.f / (float)DEG);

        // pre-scale the row once; dots then accumulate straight into acc[k]
        #pragma unroll
        for (int q = 0; q < F / 4; ++q) {
            rv[q].x *= sc; rv[q].y *= sc; rv[q].z *= sc; rv[q].w *= sc;
        }

        #pragma unroll
        for (int k = 0; k < K; ++k) {
            const int wrow = (r == 0) ? k : (K + k * DEG + (r - 1));
            float s = 0.f;
            #pragma unroll
            for (int q = 0; q < F / 4; ++q) {
                const float4 w = *(const float4*)&sW[wrow * F + q * 4];  // uniform broadcast
                s += w.x * rv[q].x + w.y * rv[q].y + w.z * rv[q].z + w.w * rv[q].w;
            }
            if (r == 0) acc[k] = s; else acc[k] += s;
        }
    }

    const int b = DEG - 1;
    o[b * 4 + 0] = make_float4(acc[0],  acc[1],  acc[2],  acc[3]);
    o[b * 4 + 1] = make_float4(acc[4],  acc[5],  acc[6],  acc[7]);
    o[b * 4 + 2] = make_float4(acc[8],  acc[9],  acc[10], acc[11]);
    o[b * 4 + 3] = make_float4(acc[12], acc[13], acc[14], acc[15]);
}

struct Args {
    const float* x;
    const int*   sel[4];
    const int*   nei[4];
    const float* Wf[4];
    const float* Wn[4];
    int nd[4];
    int bcum[4];   // cumulative block counts: after deg1, deg1+2, ...
};

// (256, 4): min 4 waves/EU -> VGPR cap 128 -> 4 blocks/CU (16 waves), vs the
// uncapped build's 132 VGPR which fell to 2 blocks/CU. Only a 4-reg squeeze:
// no spill risk (spill canary = WRITE_SIZE >> 250 MB).
__global__ __launch_bounds__(256, 4)
void fused_kernel(Args a, float* __restrict__ out)
{
    __shared__ float sW[K * 5 * F];   // max NW (deg4: 80 rows) * 32 = 10 KB
    const int bid = blockIdx.x;

    if (bid < a.bcum[0]) {
        process_deg<1>(a.x, a.sel[0], a.nei[0], a.Wf[0], a.Wn[0], out,
                       a.nd[0], bid * 256, sW);
    } else if (bid < a.bcum[1]) {
        process_deg<2>(a.x, a.sel[1], a.nei[1], a.Wf[1], a.Wn[1], out,
                       a.nd[1], (bid - a.bcum[0]) * 256, sW);
    } else if (bid < a.bcum[2]) {
        process_deg<3>(a.x, a.sel[2], a.nei[2], a.Wf[2], a.Wn[2], out,
                       a.nd[2], (bid - a.bcum[1]) * 256, sW);
    } else {
        process_deg<4>(a.x, a.sel[3], a.nei[3], a.Wf[3], a.Wn[3], out,
                       a.nd[3], (bid - a.bcum[2]) * 256, sW);
    }
}

extern "C" void kernel_launch(void* const* d_in, const int* in_sizes, int n_in,
                              void* d_out, int out_size, void* d_ws, size_t ws_size,
                              hipStream_t stream)
{
    Args a;
    a.x = (const float*)d_in[0];
    for (int d = 0; d < 4; ++d) {
        a.sel[d] = (const int*)  d_in[1 + 4 * d];
        a.nei[d] = (const int*)  d_in[2 + 4 * d];
        a.Wf[d]  = (const float*)d_in[3 + 4 * d];
        a.Wn[d]  = (const float*)d_in[4 + 4 * d];
        a.nd[d]  = in_sizes[1 + 4 * d];
    }
    int cum = 0;
    for (int d = 0; d < 4; ++d) {
        cum += (a.nd[d] + 255) / 256;
        a.bcum[d] = cum;
    }
    float* out = (float*)d_out;
    fused_kernel<<<cum, 256, 0, stream>>>(a, out);
}

// Round 5
// 683.839 us; speedup vs baseline: 2.7071x; 1.3216x over previous
//
#include <hip/hip_runtime.h>
#include <math.h>

#define F 32
#define K 16
#define EPSN 1e-8f

// Per-degree worker: block handles 256 consecutive focal nodes of one degree.
// sW: per-block LDS holding the normalized W rows for this degree
// (rows 0..15 = W_focal, rows 16.. = W_nei flat (k*DEG+j)).
//
// Hard-won rules (rounds 1/3/4):
//  - W stays in LDS as uniform ds_read_b128 broadcasts. Register-tiled or
//    scalar-pipe W explodes live ranges -> scratch -> GBs of spill traffic.
//  - Every local array index compile-time constant (rule #20).
//  - __launch_bounds__ arg2 maps EMPIRICALLY to budget 256/arg2 on this
//    toolchain (arg2=4 gave 64-VGPR builds 3x). arg2=2 -> 128 cap.
//  - 32-bit voffsets (node*32 < 2^32) save address VGPRs + VALU.
template<int DEG>
__device__ __forceinline__ void process_deg(const float* __restrict__ x,
                                            const int*   __restrict__ sel,
                                            const int*   __restrict__ nei,
                                            const float* __restrict__ Wf,
                                            const float* __restrict__ Wn,
                                            float* __restrict__ out,
                                            int nd, int i0, float* sW)
{
    constexpr int NW = K * (1 + DEG);
    const int tid = threadIdx.x;

    // normalize W rows into LDS (one thread per row; NW <= 80)
    if (tid < NW) {
        const float* src = (tid < K) ? (Wf + tid * F) : (Wn + (tid - K) * F);
        float ss = 0.f;
        #pragma unroll
        for (int f = 0; f < F; ++f) { float v = src[f]; ss += v * v; }
        const float sc = 1.f / (sqrtf(ss) + EPSN);
        #pragma unroll
        for (int f = 0; f < F; ++f) sW[tid * F + f] = src[f] * sc;
    }
    __syncthreads();

    const int i = i0 + tid;
    if (i >= nd) return;

    const int node = sel[i];

    // neighbor index loads issue immediately (coalesced)
    int nn[DEG];
    #pragma unroll
    for (int j = 0; j < DEG; ++j) nn[j] = nei[i * DEG + j];

    // Zero quadrants first: depend only on `node`, so the stores drain
    // under the row-gather latency. 32-bit element offset (node*64 < 2^26).
    float4* o = (float4*)(out + (unsigned)node * (unsigned)(4 * K));
    const float4 z = make_float4(0.f, 0.f, 0.f, 0.f);
    #pragma unroll
    for (int b = 0; b < 4; ++b) {
        if (b != DEG - 1) {
            o[b * 4 + 0] = z; o[b * 4 + 1] = z;
            o[b * 4 + 2] = z; o[b * 4 + 3] = z;
        }
    }

    float acc[K];

    #pragma unroll
    for (int r = 0; r <= DEG; ++r) {
        // 32-bit element offset: node*32 < 2^25 -> SGPR base + voffset form
        const float* xr = x + (unsigned)((r == 0) ? node : nn[r - 1]) * (unsigned)F;
        float4 rv[F / 4];
        #pragma unroll
        for (int q = 0; q < F / 4; ++q) rv[q] = ((const float4*)xr)[q];

        float ss = 0.f;
        #pragma unroll
        for (int q = 0; q < F / 4; ++q)
            ss += rv[q].x * rv[q].x + rv[q].y * rv[q].y
                + rv[q].z * rv[q].z + rv[q].w * rv[q].w;
        float sc = 1.f / (sqrtf(ss) + EPSN);
        if (r > 0) sc *= (1.f / (float)DEG);

        #pragma unroll
        for (int k = 0; k < K; ++k) {
            const int wrow = (r == 0) ? k : (K + k * DEG + (r - 1));
            float s = 0.f;
            #pragma unroll
            for (int q = 0; q < F / 4; ++q) {
                const float4 w = *(const float4*)&sW[wrow * F + q * 4];  // uniform broadcast
                s += w.x * rv[q].x + w.y * rv[q].y + w.z * rv[q].z + w.w * rv[q].w;
            }
            // one v_fmac per k (cheaper than pre-scaling the row: 16 vs 32 ops)
            if (r == 0) acc[k] = s * sc; else acc[k] += s * sc;
        }
    }

    const int b = DEG - 1;
    o[b * 4 + 0] = make_float4(acc[0],  acc[1],  acc[2],  acc[3]);
    o[b * 4 + 1] = make_float4(acc[4],  acc[5],  acc[6],  acc[7]);
    o[b * 4 + 2] = make_float4(acc[8],  acc[9],  acc[10], acc[11]);
    o[b * 4 + 3] = make_float4(acc[12], acc[13], acc[14], acc[15]);
}

struct Args {
    const float* x;
    const int*   sel[4];
    const int*   nei[4];
    const float* Wf[4];
    const float* Wn[4];
    int nd[4];
    int bcum[4];   // cumulative block counts: after deg1, deg1+2, ...
};

// arg2=2: empirical budget 256/2 = 128 VGPR (graceful 4-reg squeeze from the
// natural 132 -> 4 waves/SIMD). If the mapping is 512/arg2 instead, this is a
// no-op and we keep round-0 behavior — bounded downside.
// Spill canary: WRITE_SIZE >> 250 MB.
__global__ __launch_bounds__(256, 2)
void fused_kernel(Args a, float* __restrict__ out)
{
    __shared__ float sW[K * 5 * F];   // max NW (deg4: 80 rows) * 32 = 10 KB
    const int bid = blockIdx.x;

    if (bid < a.bcum[0]) {
        process_deg<1>(a.x, a.sel[0], a.nei[0], a.Wf[0], a.Wn[0], out,
                       a.nd[0], bid * 256, sW);
    } else if (bid < a.bcum[1]) {
        process_deg<2>(a.x, a.sel[1], a.nei[1], a.Wf[1], a.Wn[1], out,
                       a.nd[1], (bid - a.bcum[0]) * 256, sW);
    } else if (bid < a.bcum[2]) {
        process_deg<3>(a.x, a.sel[2], a.nei[2], a.Wf[2], a.Wn[2], out,
                       a.nd[2], (bid - a.bcum[1]) * 256, sW);
    } else {
        process_deg<4>(a.x, a.sel[3], a.nei[3], a.Wf[3], a.Wn[3], out,
                       a.nd[3], (bid - a.bcum[2]) * 256, sW);
    }
}

extern "C" void kernel_launch(void* const* d_in, const int* in_sizes, int n_in,
                              void* d_out, int out_size, void* d_ws, size_t ws_size,
                              hipStream_t stream)
{
    Args a;
    a.x = (const float*)d_in[0];
    for (int d = 0; d < 4; ++d) {
        a.sel[d] = (const int*)  d_in[1 + 4 * d];
        a.nei[d] = (const int*)  d_in[2 + 4 * d];
        a.Wf[d]  = (const float*)d_in[3 + 4 * d];
        a.Wn[d]  = (const float*)d_in[4 + 4 * d];
        a.nd[d]  = in_sizes[1 + 4 * d];
    }
    int cum = 0;
    for (int d = 0; d < 4; ++d) {
        cum += (a.nd[d] + 255) / 256;
        a.bcum[d] = cum;
    }
    float* out = (float*)d_out;
    fused_kernel<<<cum, 256, 0, stream>>>(a, out);
}

// Round 6
// 491.538 us; speedup vs baseline: 3.7661x; 1.3912x over previous
//
#include <hip/hip_runtime.h>
#include <math.h>

#define F 32
#define K 16
#define EPSN 1e-8f

// Quad-per-node decomposition.
//
// Why (rounds 0-5): thread-per-node needs acc[16]+rv[32]+addr ~= 132 VGPR —
// permanently 4 regs over the 128 occupancy cliff; every attempt to cap or
// restructure (launch_bounds 4/2, reg double-buffer, scalar-pipe W) spilled
// to scratch and added 0.5-2 GB of HBM traffic. Splitting each node across
// a 4-lane quad (lane p owns row slice [8p,8p+8)) cuts per-thread state to
// ~50 VGPR -> natural max occupancy, no cap, no spill risk.
//
// LDS W layout: pitch 32 floats, rows 0..15 = W_focal, 16.. = W_nei (k*DEG+j).
// Per ds_read_b128 the wave presents only 4 distinct addresses (depends only
// on p); 16x same-address broadcast is free and the 4 slices hit disjoint
// bank quartets -> zero bank conflicts (was 1.53M).
__device__ __forceinline__ float dot4(const float4 a, const float4 b) {
    return a.x*b.x + a.y*b.y + a.z*b.z + a.w*b.w;
}

template<int DEG>
__device__ __forceinline__ void process_deg(const float* __restrict__ x,
                                            const int*   __restrict__ sel,
                                            const int*   __restrict__ nei,
                                            const float* __restrict__ Wf,
                                            const float* __restrict__ Wn,
                                            float* __restrict__ out,
                                            int nd, int i0, float* sW)
{
    constexpr int NW = K * (1 + DEG);
    const int tid = threadIdx.x;

    // normalize W rows into LDS (one thread per row; NW <= 80)
    if (tid < NW) {
        const float* src = (tid < K) ? (Wf + tid * F) : (Wn + (tid - K) * F);
        float ss = 0.f;
        #pragma unroll
        for (int f = 0; f < F; ++f) { float v = src[f]; ss += v * v; }
        const float sc = 1.f / (sqrtf(ss) + EPSN);
        #pragma unroll
        for (int f = 0; f < F; ++f) sW[tid * F + f] = src[f] * sc;
    }
    __syncthreads();

    const int quad  = tid >> 2;     // 0..63 : node slot within this iteration
    const int p     = tid & 3;      // slice owner: floats [8p, 8p+8)
    const int pbase = p * 8;

    // Block covers 256 nodes in 4 iterations of 64 quads.
    // unroll 1: protect the <=64-VGPR budget; latency hiding comes from TLP
    // (8 waves/SIMD at this register count).
    #pragma unroll 1
    for (int it = 0; it < 4; ++it) {
        const int i = i0 + it * 64 + quad;
        if (i >= nd) continue;               // uniform per quad

        const int node = sel[i];
        int nn[DEG];
        #pragma unroll
        for (int j = 0; j < DEG; ++j) nn[j] = nei[i * DEG + j];

        float acc[K];

        #pragma unroll
        for (int r = 0; r <= DEG; ++r) {
            const unsigned row = (unsigned)((r == 0) ? node : nn[r - 1]);
            const float* xr = x + row * (unsigned)F + pbase;   // 32-bit offset
            const float4 rv0 = *(const float4*)(xr);
            const float4 rv1 = *(const float4*)(xr + 4);

            // row squared-norm: per-slice partial, then quad butterfly
            float ss = dot4(rv0, rv0) + dot4(rv1, rv1);
            ss += __shfl_xor(ss, 1);
            ss += __shfl_xor(ss, 2);
            float sc = 1.f / (sqrtf(ss) + EPSN);
            if (r > 0) sc *= (1.f / (float)DEG);

            #pragma unroll
            for (int k = 0; k < K; ++k) {
                const int wrow = (r == 0) ? k : (K + k * DEG + (r - 1));
                const float4 w0 = *(const float4*)&sW[wrow * F + pbase];
                const float4 w1 = *(const float4*)&sW[wrow * F + pbase + 4];
                const float d = dot4(w0, rv0) + dot4(w1, rv1);
                if (r == 0) acc[k] = d * sc;
                else        acc[k] = fmaf(d, sc, acc[k]);
            }
        }

        // reduce slice-partials across the quad (all 4 lanes end with full acc)
        #pragma unroll
        for (int k = 0; k < K; ++k) {
            acc[k] += __shfl_xor(acc[k], 1);
            acc[k] += __shfl_xor(acc[k], 2);
        }

        // each lane stores its 64-byte chunk of the 256-byte output row;
        // band (DEG-1)*16..DEG*16 is exactly lane p==DEG-1's chunk.
        float4* o = (float4*)(out + (size_t)node * (4 * K) + p * 16);
        if (p == DEG - 1) {
            o[0] = make_float4(acc[0],  acc[1],  acc[2],  acc[3]);
            o[1] = make_float4(acc[4],  acc[5],  acc[6],  acc[7]);
            o[2] = make_float4(acc[8],  acc[9],  acc[10], acc[11]);
            o[3] = make_float4(acc[12], acc[13], acc[14], acc[15]);
        } else {
            const float4 z = make_float4(0.f, 0.f, 0.f, 0.f);
            o[0] = z; o[1] = z; o[2] = z; o[3] = z;
        }
    }
}

struct Args {
    const float* x;
    const int*   sel[4];
    const int*   nei[4];
    const float* Wf[4];
    const float* Wn[4];
    int nd[4];
    int bcum[4];   // cumulative block counts: after deg1, deg1+2, ...
};

// NO second launch_bounds arg: rounds 1/3/4/5 proved any forced VGPR budget
// below natural use spills catastrophically. This structure's natural use
// (~50) sits far under 64, giving max occupancy without coercion.
__global__ __launch_bounds__(256)
void fused_kernel(Args a, float* __restrict__ out)
{
    __shared__ float sW[K * 5 * F];   // max NW (deg4: 80 rows) * 32 = 10 KB
    const int bid = blockIdx.x;

    if (bid < a.bcum[0]) {
        process_deg<1>(a.x, a.sel[0], a.nei[0], a.Wf[0], a.Wn[0], out,
                       a.nd[0], bid * 256, sW);
    } else if (bid < a.bcum[1]) {
        process_deg<2>(a.x, a.sel[1], a.nei[1], a.Wf[1], a.Wn[1], out,
                       a.nd[1], (bid - a.bcum[0]) * 256, sW);
    } else if (bid < a.bcum[2]) {
        process_deg<3>(a.x, a.sel[2], a.nei[2], a.Wf[2], a.Wn[2], out,
                       a.nd[2], (bid - a.bcum[1]) * 256, sW);
    } else {
        process_deg<4>(a.x, a.sel[3], a.nei[3], a.Wf[3], a.Wn[3], out,
                       a.nd[3], (bid - a.bcum[2]) * 256, sW);
    }
}

extern "C" void kernel_launch(void* const* d_in, const int* in_sizes, int n_in,
                              void* d_out, int out_size, void* d_ws, size_t ws_size,
                              hipStream_t stream)
{
    Args a;
    a.x = (const float*)d_in[0];
    for (int d = 0; d < 4; ++d) {
        a.sel[d] = (const int*)  d_in[1 + 4 * d];
        a.nei[d] = (const int*)  d_in[2 + 4 * d];
        a.Wf[d]  = (const float*)d_in[3 + 4 * d];
        a.Wn[d]  = (const float*)d_in[4 + 4 * d];
        a.nd[d]  = in_sizes[1 + 4 * d];
    }
    int cum = 0;
    for (int d = 0; d < 4; ++d) {
        cum += (a.nd[d] + 255) / 256;
        a.bcum[d] = cum;
    }
    float* out = (float*)d_out;
    fused_kernel<<<cum, 256, 0, stream>>>(a, out);
}

// Round 8
// 443.012 us; speedup vs baseline: 4.1787x; 1.1095x over previous
//
#include <hip/hip_runtime.h>
#include <math.h>

#define F 32
#define K 16
#define EPSN 1e-8f

// MFMA reformulation.
//
// Per 16 nodes (one wave-group) and per receptive-field row-slab r
// (r=0: focal, r>0: neighbor r-1), the update
//     scores(16k x 16nodes) += W_hat_r(16 x 32f) . X_hat_r(32f x 16nodes)
// is ONE v_mfma_f32_16x16x32_f16. This kills the two round-6 walls at once:
//   - LDS:  32 ds_read_b128 per (slab, wave) -> 2 (A-fragment hi/lo)
//   - VALU: 16k x 8 FMA/lane per slab        -> norm + f32->f16 cvt only
// and live state drops to ~60 VGPR (acc f32x4, no W software pipeline).
//
// Precision: f16 rounds at 2^-11 -> dot err ~1e-3 vs 2^-8 tolerance. Split
// BOTH operands hi/lo (lo = v - (f16)v) and do 3 MFMAs per slab:
// Ah.Bh + Ah.Bl + Al.Bh  (Al.Bl ~ 2^-22, dropped) -> err ~1e-5.
//
// Fragment layouts (m89-verified C/D; standard gfx950 A/B):
//   A[i][k]: lane l holds row i=l&15, k = 8*(l>>4)+e (e=0..7)
//   B[k][j]: lane l holds col j=l&15, k = 8*(l>>4)+e
//   D[i][j]: lane l holds col j=l&15, rows i = (l>>4)*4+reg
// So lane l: node = l&15, feature-slice/k-quartet owner kq = l>>4.

typedef _Float16 half8 __attribute__((ext_vector_type(8)));
typedef float f32x4  __attribute__((ext_vector_type(4)));

template<int DEG>
__device__ __forceinline__ void process_deg(const float* __restrict__ x,
                                            const int*   __restrict__ sel,
                                            const int*   __restrict__ nei,
                                            const float* __restrict__ Wf,
                                            const float* __restrict__ Wn,
                                            float* __restrict__ out,
                                            int nd, int i0,
                                            _Float16* sWh, _Float16* sWl)
{
    constexpr int R  = 1 + DEG;
    constexpr int NW = K * R;
    const int tid = threadIdx.x;

    // ---- preamble: normalize W rows, hi/lo split, scatter into A-layout ----
    // A-slab r occupies halves [r*512, r*512+512): lane l's fragment at
    // r*512 + l*8. Element (k, f) lives at lane k+16*(f>>3), elem f&7.
    if (tid < NW) {
        const float* src = (tid < K) ? (Wf + tid * F) : (Wn + (tid - K) * F);
        float ss = 0.f;
        #pragma unroll
        for (int f = 0; f < F; ++f) { const float t = src[f]; ss += t * t; }
        const float sc = 1.f / (sqrtf(ss) + EPSN);
        const int t = tid - K;
        const int r = (tid < K) ? 0   : (1 + t % DEG);
        const int k = (tid < K) ? tid : (t / DEG);
        #pragma unroll
        for (int f = 0; f < F; ++f) {               // re-read src (L1) — avoids
            const float wv = src[f] * sc;           // a 32-reg live transient
            const _Float16 hi = (_Float16)wv;
            const _Float16 lo = (_Float16)(wv - (float)hi);
            const int off = r * 512 + (k + 16 * (f >> 3)) * 8 + (f & 7);
            sWh[off] = hi; sWl[off] = lo;
        }
    }
    __syncthreads();

    const int lane = tid & 63;
    const int wv   = tid >> 6;        // wave id 0..3
    const int jcol = lane & 15;       // node slot within the wave's 16
    const int kq   = lane >> 4;       // feature-block / k-quartet owner
    const float invdeg = 1.f / (float)DEG;

    #pragma unroll 1
    for (int it = 0; it < 4; ++it) {
        int i = i0 + it * 64 + wv * 16 + jcol;
        const bool valid = (i < nd);
        if (!valid) i = nd - 1;       // clamp: lanes stay alive for MFMA/shfl

        const int node = sel[i];
        int nn[DEG];
        #pragma unroll
        for (int j = 0; j < DEG; ++j) nn[j] = nei[i * DEG + j];

        f32x4 acc = {0.f, 0.f, 0.f, 0.f};

        #pragma unroll
        for (int r = 0; r < R; ++r) {
            const unsigned row = (unsigned)((r == 0) ? node : nn[r - 1]);
            const float* xr = x + row * (unsigned)F + kq * 8;
            const float4 a0 = *(const float4*)(xr);
            const float4 a1 = *(const float4*)(xr + 4);

            // row squared-norm: 8-elem partial, reduce across slice-mates
            // (lanes l, l^16, l^32, l^48 hold the same node's 4 slices)
            float ss = a0.x*a0.x + a0.y*a0.y + a0.z*a0.z + a0.w*a0.w
                     + a1.x*a1.x + a1.y*a1.y + a1.z*a1.z + a1.w*a1.w;
            ss += __shfl_xor(ss, 16);
            ss += __shfl_xor(ss, 32);
            float sc = 1.f / (sqrtf(ss) + EPSN);
            if (r > 0) sc *= invdeg;

            const float f0 = a0.x*sc, f1 = a0.y*sc, f2 = a0.z*sc, f3 = a0.w*sc;
            const float f4 = a1.x*sc, f5 = a1.y*sc, f6 = a1.z*sc, f7 = a1.w*sc;

            half8 bh, bl;
            bh[0]=(_Float16)f0; bl[0]=(_Float16)(f0-(float)bh[0]);
            bh[1]=(_Float16)f1; bl[1]=(_Float16)(f1-(float)bh[1]);
            bh[2]=(_Float16)f2; bl[2]=(_Float16)(f2-(float)bh[2]);
            bh[3]=(_Float16)f3; bl[3]=(_Float16)(f3-(float)bh[3]);
            bh[4]=(_Float16)f4; bl[4]=(_Float16)(f4-(float)bh[4]);
            bh[5]=(_Float16)f5; bl[5]=(_Float16)(f5-(float)bh[5]);
            bh[6]=(_Float16)f6; bl[6]=(_Float16)(f6-(float)bh[6]);
            bh[7]=(_Float16)f7; bl[7]=(_Float16)(f7-(float)bh[7]);

            const int aoff = r * 512 + lane * 8;
            const half8 ah = *(const half8*)(sWh + aoff);
            const half8 al = *(const half8*)(sWl + aoff);

            acc = __builtin_amdgcn_mfma_f32_16x16x32_f16(ah, bh, acc, 0, 0, 0);
            acc = __builtin_amdgcn_mfma_f32_16x16x32_f16(ah, bl, acc, 0, 0, 0);
            acc = __builtin_amdgcn_mfma_f32_16x16x32_f16(al, bh, acc, 0, 0, 0);
        }

        // lane l holds D rows k = kq*4+reg for node jcol. Non-zero band is
        // float4 position (DEG-1)*4 + kq; lane also zeroes positions b*4+kq
        // for the other 3 bands -> the 4 lanes of a node cover all 16.
        if (valid) {
            float* orow = out + (size_t)node * (4 * K);
            #pragma unroll
            for (int b = 0; b < 4; ++b) {
                float4 vst = make_float4(0.f, 0.f, 0.f, 0.f);
                if (b == DEG - 1)
                    vst = make_float4(acc[0], acc[1], acc[2], acc[3]);
                *(float4*)(orow + (b * 4 + kq) * 4) = vst;
            }
        }
    }
}

struct Args {
    const float* x;
    const int*   sel[4];
    const int*   nei[4];
    const float* Wf[4];
    const float* Wn[4];
    int nd[4];
    int bcum[4];   // cumulative block counts: after deg1, deg1+2, ...
};

// No second launch_bounds arg (rounds 1/3/4/5: any forced cap below natural
// use spills catastrophically). Natural use here ~60 VGPR.
__global__ __launch_bounds__(256)
void fused_kernel(Args a, float* __restrict__ out)
{
    __shared__ __align__(16) _Float16 sWh[5 * 512];   // 5 slabs x 1 KB
    __shared__ __align__(16) _Float16 sWl[5 * 512];
    const int bid = blockIdx.x;

    if (bid < a.bcum[0]) {
        process_deg<1>(a.x, a.sel[0], a.nei[0], a.Wf[0], a.Wn[0], out,
                       a.nd[0], bid * 256, sWh, sWl);
    } else if (bid < a.bcum[1]) {
        process_deg<2>(a.x, a.sel[1], a.nei[1], a.Wf[1], a.Wn[1], out,
                       a.nd[1], (bid - a.bcum[0]) * 256, sWh, sWl);
    } else if (bid < a.bcum[2]) {
        process_deg<3>(a.x, a.sel[2], a.nei[2], a.Wf[2], a.Wn[2], out,
                       a.nd[2], (bid - a.bcum[1]) * 256, sWh, sWl);
    } else {
        process_deg<4>(a.x, a.sel[3], a.nei[3], a.Wf[3], a.Wn[3], out,
                       a.nd[3], (bid - a.bcum[2]) * 256, sWh, sWl);
    }
}

extern "C" void kernel_launch(void* const* d_in, const int* in_sizes, int n_in,
                              void* d_out, int out_size, void* d_ws, size_t ws_size,
                              hipStream_t stream)
{
    Args a;
    a.x = (const float*)d_in[0];
    for (int d = 0; d < 4; ++d) {
        a.sel[d] = (const int*)  d_in[1 + 4 * d];
        a.nei[d] = (const int*)  d_in[2 + 4 * d];
        a.Wf[d]  = (const float*)d_in[3 + 4 * d];
        a.Wn[d]  = (const float*)d_in[4 + 4 * d];
        a.nd[d]  = in_sizes[1 + 4 * d];
    }
    int cum = 0;
    for (int d = 0; d < 4; ++d) {
        cum += (a.nd[d] + 255) / 256;
        a.bcum[d] = cum;
    }
    float* out = (float*)d_out;
    fused_kernel<<<cum, 256, 0, stream>>>(a, out);
}